// Round 10
// baseline (116.283 us; speedup 1.0000x reference)
//
#include <hip/hip_runtime.h>
#include <math.h>

typedef __attribute__((ext_vector_type(8))) short short8;
typedef __attribute__((ext_vector_type(4))) short shortx4;
typedef __attribute__((ext_vector_type(4))) float floatx4;

__device__ __forceinline__ float siluf(float v) { return v / (1.f + expf(-v)); }

__device__ __forceinline__ short f2bf(float f) {
    unsigned u = __float_as_uint(f);
    u += 0x7fffu + ((u >> 16) & 1u);
    return (short)(u >> 16);
}

// slice strides
#define SL2 ((size_t)128 * 1536)  // xd
#define SLD ((size_t)128 * 2048)  // dacc
#define SLM ((size_t)128 * 1024)  // mo
#define SLZ ((size_t)128 * 512)   // zd

// ---- 64x64 weight tile transpose+cvt: dst[n][k] = bf16(src[k][n]) ----
__device__ __forceinline__ void tile_transpose(const float* __restrict__ src,
                                               short* __restrict__ dst,
                                               int K, int N, int t,
                                               short tl[64][68]) {
    const int tid = threadIdx.x;
    int ntn = N >> 6;
    int k0 = (t / ntn) << 6;
    int n0 = (t % ntn) << 6;
    int rr = tid >> 4, c4 = (tid & 15) * 4;
#pragma unroll
    for (int p = 0; p < 4; ++p) {
        int r = p * 16 + rr;
        float4 v = *(const float4*)&src[(size_t)(k0 + r) * N + n0 + c4];
        shortx4 sv;
        sv[0] = f2bf(v.x); sv[1] = f2bf(v.y); sv[2] = f2bf(v.z); sv[3] = f2bf(v.w);
        *(shortx4*)&tl[r][c4] = sv;
    }
    __syncthreads();
#pragma unroll
    for (int p = 0; p < 4; ++p) {
        int n = p * 16 + rr;
        shortx4 o;
        o[0] = tl[c4 + 0][n]; o[1] = tl[c4 + 1][n];
        o[2] = tl[c4 + 2][n]; o[3] = tl[c4 + 3][n];
        *(shortx4*)&dst[(size_t)(n0 + n) * K + k0 + c4] = o;
    }
}

// ---- A-fragment loader ----
// MODE 0: bf16 A (lda in shorts); MODE 1: sum NS f32 slices; MODE 2: + aux0[j] + aux1[r*lda+j]
template<int MODE, int NS>
__device__ __forceinline__ short8 a_frag(const void* __restrict__ A, int lda, size_t SL,
                                         int r, int j0,
                                         const float* __restrict__ aux0,
                                         const float* __restrict__ aux1) {
    if constexpr (MODE == 0) {
        return *(const short8*)((const short*)A + (size_t)r * lda + j0);
    } else {
        const float* Af = (const float*)A;
        size_t base = (size_t)r * lda + j0;
        short8 sv;
#pragma unroll
        for (int i = 0; i < 8; ++i) {
            float t = 0.f;
#pragma unroll
            for (int s = 0; s < NS; ++s) t += Af[(size_t)s * SL + base + i];
            if constexpr (MODE == 2) t += aux0[j0 + i] + aux1[base + i];
            sv[i] = f2bf(t);
        }
        return sv;
    }
}

// ---- GEMM core: 256 thr = 4 waves; wave w rows [w*32,+32); NT n-frags (BN=16*NT) at n0; K-chunk at k0 ----
// acc[mf][nt][r] -> row = (tid>>6)*32 + ((tid&63)>>4)*4 + mf*16 + r, col = n0 + nt*16 + (tid&15)
template<int MODE, int NS, int KSTEPS, int NT>
__device__ __forceinline__ void gemm_core(const void* __restrict__ A, int lda, size_t SL,
                                          const float* __restrict__ aux0,
                                          const float* __restrict__ aux1,
                                          const short* __restrict__ Bt, int K,
                                          int n0, int k0, floatx4 (&acc)[2][NT]) {
    const int tid = threadIdx.x;
    const int w = tid >> 6;
    const int l = tid & 63;
    const int lane15 = l & 15;
    const int lgrp = l >> 4;
    const int r0 = w * 32 + lane15;
    const short* Bp[NT];
#pragma unroll
    for (int nt = 0; nt < NT; ++nt)
        Bp[nt] = Bt + (size_t)(n0 + nt * 16 + lane15) * K + k0 + lgrp * 8;
#pragma unroll
    for (int i = 0; i < 2; ++i)
#pragma unroll
        for (int j = 0; j < NT; ++j) acc[i][j] = (floatx4)0.f;
#pragma unroll
    for (int s = 0; s < KSTEPS; ++s) {
        int j0 = k0 + s * 32 + lgrp * 8;
        short8 a0 = a_frag<MODE, NS>(A, lda, SL, r0, j0, aux0, aux1);
        short8 a1 = a_frag<MODE, NS>(A, lda, SL, r0 + 16, j0, aux0, aux1);
#pragma unroll
        for (int nt = 0; nt < NT; ++nt) {
            short8 b = *(const short8*)(Bp[nt] + s * 32);
            acc[0][nt] = __builtin_amdgcn_mfma_f32_16x16x32_bf16(a0, b, acc[0][nt], 0, 0, 0);
            acc[1][nt] = __builtin_amdgcn_mfma_f32_16x16x32_bf16(a1, b, acc[1][nt], 0, 0, 0);
        }
    }
}

#define EPI_IDX \
    const int tid = threadIdx.x; \
    const int lane15 = tid & 15; \
    const int rb = (tid >> 6) * 32 + ((tid & 63) >> 4) * 4;

// ---------------- prep: LN (0..127) + transpose W_in (128..1151) + W_f (1152..1279) ----------------
__global__ __launch_bounds__(256) void prep_kernel(
        const float* __restrict__ x, const float* __restrict__ ln_g,
        const float* __restrict__ ln_b, const float* __restrict__ c,
        const float* __restrict__ W_in, const float* __restrict__ W_f,
        short* __restrict__ h_bf, short* __restrict__ c_bf,
        short* __restrict__ wt_in, short* __restrict__ wt_f) {
    __shared__ short tl[64][68];
    const int tid = threadIdx.x;
    if (blockIdx.x < 128) {
        __shared__ float sdata[256];
        int b = blockIdx.x;
        const float* xr = x + b * 1024;
        float v[4];
        float s = 0.f;
#pragma unroll
        for (int i = 0; i < 4; ++i) { v[i] = xr[tid + i * 256]; s += v[i]; }
        sdata[tid] = s; __syncthreads();
        for (int st = 128; st > 0; st >>= 1) { if (tid < st) sdata[tid] += sdata[tid + st]; __syncthreads(); }
        float mu = sdata[0] * (1.f / 1024.f);
        __syncthreads();
        float s2 = 0.f;
#pragma unroll
        for (int i = 0; i < 4; ++i) { float d = v[i] - mu; s2 += d * d; }
        sdata[tid] = s2; __syncthreads();
        for (int st = 128; st > 0; st >>= 1) { if (tid < st) sdata[tid] += sdata[tid + st]; __syncthreads(); }
        float inv = rsqrtf(sdata[0] * (1.f / 1024.f) + 1e-5f);
        short* hr = h_bf + b * 1024;
#pragma unroll
        for (int i = 0; i < 4; ++i) {
            int j = tid + i * 256;
            hr[j] = f2bf((v[i] - mu) * inv * ln_g[j] + ln_b[j]);
        }
        const float* cr = c + b * 512;
        short* cbr = c_bf + b * 512;
        cbr[tid] = f2bf(cr[tid]);
        cbr[tid + 256] = f2bf(cr[tid + 256]);
    } else if (blockIdx.x < 1152) {
        tile_transpose(W_in, wt_in, 1024, 4096, blockIdx.x - 128, tl);
    } else {
        tile_transpose(W_f, wt_f, 512, 1024, blockIdx.x - 1152, tl);
    }
}

// ---------------- g1g6: G1 full-K fused-e1 (0..127) + G6 full-K (128..159) + T(W_x,W_dt) ----------------
__global__ __launch_bounds__(256) void g1g6_kernel(
        const short* __restrict__ h_bf, const short* __restrict__ wt_in,
        const short* __restrict__ c_bf, const short* __restrict__ wt_f,
        const float* __restrict__ cw3, const float* __restrict__ cb,
        const float* __restrict__ W_x, const float* __restrict__ W_dt,
        float* __restrict__ u_f32, short* __restrict__ u_bf,
        float* __restrict__ sres, float* __restrict__ gb,
        short* __restrict__ wt_x, short* __restrict__ wt_dt) {
    __shared__ short tl[64][68];
    int bid = blockIdx.x;
    if (bid < 128) {
        floatx4 acc[2][2];
        int n0 = bid * 32;
        gemm_core<0, 0, 32, 2>(h_bf, 1024, 0, nullptr, nullptr, wt_in, 1024, n0, 0, acc);
        EPI_IDX
#pragma unroll
        for (int mf = 0; mf < 2; ++mf)
#pragma unroll
            for (int nt = 0; nt < 2; ++nt)
#pragma unroll
                for (int r = 0; r < 4; ++r) {
                    int row = rb + mf * 16 + r;
                    int col = n0 + nt * 16 + lane15;
                    float val = acc[mf][nt][r];
                    if (col < 2048) {
                        float u = siluf(val * cw3[col] + cb[col]);
                        u_f32[(size_t)row * 2048 + col] = u;
                        u_bf[(size_t)row * 2048 + col] = f2bf(u);
                    } else {
                        sres[(size_t)row * 2048 + col - 2048] = siluf(val);
                    }
                }
    } else if (bid < 160) {
        floatx4 acc[2][2];
        int n0 = (bid - 128) * 32;   // 32 blocks x 32 cols = 1024 = full gb width
        gemm_core<0, 0, 16, 2>(c_bf, 512, 0, nullptr, nullptr, wt_f, 512, n0, 0, acc);
        EPI_IDX
#pragma unroll
        for (int mf = 0; mf < 2; ++mf)
#pragma unroll
            for (int nt = 0; nt < 2; ++nt)
#pragma unroll
                for (int r = 0; r < 4; ++r)
                    gb[(size_t)(rb + mf * 16 + r) * 1024 + n0 + nt * 16 + lane15] = acc[mf][nt][r];
    } else if (bid < 928) {
        tile_transpose(W_x, wt_x, 2048, 1536, bid - 160, tl);
    } else {
        tile_transpose(W_dt, wt_dt, 512, 2048, bid - 928, tl);
    }
}

// ---------------- g2: split-2 (0..95) -> xd 2 slices  + T(W_out, W_d) ----------------
__global__ __launch_bounds__(256) void g2_kernel(const short* __restrict__ u_bf,
                                                 const short* __restrict__ wt_x,
                                                 const float* __restrict__ W_out,
                                                 const float* __restrict__ W_d,
                                                 float* __restrict__ xd_p,
                                                 short* __restrict__ wt_out,
                                                 short* __restrict__ wt_d) {
    __shared__ short tl[64][68];
    int bid = blockIdx.x;
    if (bid < 96) {
        floatx4 acc[2][2];
        int nb = bid >> 1, ks = bid & 1;
        int n0 = nb * 32;
        gemm_core<0, 0, 32, 2>(u_bf, 2048, 0, nullptr, nullptr, wt_x, 2048, n0, ks * 1024, acc);
        float* Cs = xd_p + (size_t)ks * SL2;
        EPI_IDX
#pragma unroll
        for (int mf = 0; mf < 2; ++mf)
#pragma unroll
            for (int nt = 0; nt < 2; ++nt)
#pragma unroll
                for (int r = 0; r < 4; ++r)
                    Cs[(size_t)(rb + mf * 16 + r) * 1536 + n0 + nt * 16 + lane15] = acc[mf][nt][r];
    } else if (bid < 608) {
        tile_transpose(W_out, wt_out, 2048, 1024, bid - 96, tl);
    } else {
        tile_transpose(W_d, wt_d, 1024, 512, bid - 608, tl);
    }
}

// ---------------- g3: dr(sum 2 xd slices) @ wt_dt, BN=64, split-2 -> dacc 2 slices (64 blk) ----------------
__global__ __launch_bounds__(256) void g3_kernel(const float* __restrict__ xd_p,
                                                 const short* __restrict__ wt_dt,
                                                 float* __restrict__ dacc_p) {
    floatx4 acc[2][4];
    int nb = blockIdx.x >> 1, ks = blockIdx.x & 1;
    int n0 = nb * 64;
    gemm_core<1, 2, 8, 4>(xd_p, 1536, SL2, nullptr, nullptr, wt_dt, 512, n0, ks * 256, acc);
    float* Cs = dacc_p + (size_t)ks * SLD;
    EPI_IDX
#pragma unroll
    for (int mf = 0; mf < 2; ++mf)
#pragma unroll
        for (int nt = 0; nt < 4; ++nt)
#pragma unroll
            for (int r = 0; r < 4; ++r)
                Cs[(size_t)(rb + mf * 16 + r) * 2048 + n0 + nt * 16 + lane15] = acc[mf][nt][r];
}

// ---------------- e3: per-row svec + y = u*(softplus(sum dacc+b_dt)*svec + D)*sres -> bf16 ----------------
__global__ __launch_bounds__(256) void e3_kernel(const float* __restrict__ xd_p,
                                                 const float* __restrict__ dacc_p,
                                                 const float* __restrict__ b_dt,
                                                 const float* __restrict__ u_f32,
                                                 const float* __restrict__ sres,
                                                 const float* __restrict__ Dv,
                                                 short* __restrict__ y_bf) {
    int row = blockIdx.x;
    int tid = threadIdx.x;
    __shared__ float sdata[256];
    float s = 0.f;
#pragma unroll
    for (int q = 0; q < 2; ++q) {
        int n = tid + q * 256;
        float bm = xd_p[(size_t)row * 1536 + 512 + n] + xd_p[SL2 + (size_t)row * 1536 + 512 + n];
        float cm = xd_p[(size_t)row * 1536 + 1024 + n] + xd_p[SL2 + (size_t)row * 1536 + 1024 + n];
        s += bm * cm;
    }
    sdata[tid] = s; __syncthreads();
    for (int st = 128; st > 0; st >>= 1) { if (tid < st) sdata[tid] += sdata[tid + st]; __syncthreads(); }
    float svec = sdata[0];
#pragma unroll
    for (int q = 0; q < 8; ++q) {
        int j = tid + q * 256;
        size_t idx = (size_t)row * 2048 + j;
        float t = b_dt[j] + dacc_p[idx] + dacc_p[SLD + idx];
        float delta = fmaxf(t, 0.f) + log1pf(expf(-fabsf(t)));
        y_bf[idx] = f2bf(u_f32[idx] * (delta * svec + Dv[j]) * sres[idx]);
    }
}

// ---------------- g4: split-4 -> mo 4 slices (128 blk) ----------------
__global__ __launch_bounds__(256) void g4_kernel(const short* __restrict__ y_bf,
                                                 const short* __restrict__ wt_out,
                                                 float* __restrict__ mo_p) {
    floatx4 acc[2][2];
    int nb = blockIdx.x >> 2, ks = blockIdx.x & 3;
    int n0 = nb * 32;
    gemm_core<0, 0, 16, 2>(y_bf, 2048, 0, nullptr, nullptr, wt_out, 2048, n0, ks * 512, acc);
    float* Cs = mo_p + (size_t)ks * SLM;
    EPI_IDX
#pragma unroll
    for (int mf = 0; mf < 2; ++mf)
#pragma unroll
        for (int nt = 0; nt < 2; ++nt)
#pragma unroll
            for (int r = 0; r < 4; ++r)
                Cs[(size_t)(rb + mf * 16 + r) * 1024 + n0 + nt * 16 + lane15] = acc[mf][nt][r];
}

// ---------------- g5: (sum 4 mo + b_out + x) @ wt_d, BN=64, split-4 -> zd 4 slices (32 blk) + T(W_o) ----------------
__global__ __launch_bounds__(256) void g5_kernel(const float* __restrict__ mo_p,
                                                 const float* __restrict__ b_out,
                                                 const float* __restrict__ x,
                                                 const short* __restrict__ wt_d,
                                                 const float* __restrict__ W_o,
                                                 float* __restrict__ zd_p,
                                                 short* __restrict__ wt_o) {
    __shared__ short tl[64][68];
    int bid = blockIdx.x;
    if (bid < 32) {
        floatx4 acc[2][4];
        int nb = bid >> 2, ks = bid & 3;
        int n0 = nb * 64;
        gemm_core<2, 4, 8, 4>(mo_p, 1024, SLM, b_out, x, wt_d, 1024, n0, ks * 256, acc);
        float* Cs = zd_p + (size_t)ks * SLZ;
        EPI_IDX
#pragma unroll
        for (int mf = 0; mf < 2; ++mf)
#pragma unroll
            for (int nt = 0; nt < 4; ++nt)
#pragma unroll
                for (int r = 0; r < 4; ++r)
                    Cs[(size_t)(rb + mf * 16 + r) * 512 + n0 + nt * 16 + lane15] = acc[mf][nt][r];
    } else {
        tile_transpose(W_o, wt_o, 512, 1024, bid - 32, tl);
    }
}

// ---------------- e5: z = gelu(sum 4 zd + b_d) * (gb + b_f) FiLM -> bf16 ----------------
__global__ __launch_bounds__(256) void e5_kernel(const float* __restrict__ zd_p,
                                                 const float* __restrict__ b_d,
                                                 const float* __restrict__ gb,
                                                 const float* __restrict__ b_f,
                                                 short* __restrict__ z_bf) {
#pragma unroll
    for (int q = 0; q < 4; ++q) {
        int i = blockIdx.x * 1024 + q * 256 + threadIdx.x;  // 128*512
        int row = i >> 9, n = i & 511;
        float t = b_d[n];
#pragma unroll
        for (int sl = 0; sl < 4; ++sl) t += zd_p[(size_t)sl * SLZ + i];
        float zg = 0.5f * t * (1.f + erff(t * 0.70710678118654752f));
        float gq = gb[(size_t)row * 1024 + n] + b_f[n];
        float bb = gb[(size_t)row * 1024 + 512 + n] + b_f[512 + n];
        z_bf[i] = f2bf(zg * gq + bb);
    }
}

// ---------------- g7: full-K, out = acc + b_o (32 blk) ----------------
__global__ __launch_bounds__(256) void g7_kernel(const short* __restrict__ z_bf,
                                                 const short* __restrict__ wt_o,
                                                 const float* __restrict__ b_o,
                                                 float* __restrict__ out) {
    floatx4 acc[2][2];
    int n0 = blockIdx.x * 32;
    gemm_core<0, 0, 16, 2>(z_bf, 512, 0, nullptr, nullptr, wt_o, 512, n0, 0, acc);
    EPI_IDX
#pragma unroll
    for (int mf = 0; mf < 2; ++mf)
#pragma unroll
        for (int nt = 0; nt < 2; ++nt)
#pragma unroll
            for (int r = 0; r < 4; ++r) {
                int col = n0 + nt * 16 + lane15;
                out[(size_t)(rb + mf * 16 + r) * 1024 + col] = acc[mf][nt][r] + b_o[col];
            }
}

extern "C" void kernel_launch(void* const* d_in, const int* in_sizes, int n_in,
                              void* d_out, int out_size, void* d_ws, size_t ws_size,
                              hipStream_t stream) {
    (void)in_sizes; (void)n_in; (void)out_size; (void)ws_size;
    const float* x     = (const float*)d_in[0];
    const float* c     = (const float*)d_in[1];
    const float* ln_g  = (const float*)d_in[2];
    const float* ln_b  = (const float*)d_in[3];
    const float* W_in  = (const float*)d_in[4];
    const float* convw = (const float*)d_in[5];
    const float* convb = (const float*)d_in[6];
    const float* W_x   = (const float*)d_in[7];
    const float* W_dt  = (const float*)d_in[8];
    const float* b_dt  = (const float*)d_in[9];
    // d_in[10] = A_log: unused (scan length 1 from h0 = 0)
    const float* Dv    = (const float*)d_in[11];
    const float* W_out = (const float*)d_in[12];
    const float* b_out = (const float*)d_in[13];
    const float* W_d   = (const float*)d_in[14];
    const float* b_d   = (const float*)d_in[15];
    const float* W_f   = (const float*)d_in[16];
    const float* b_f   = (const float*)d_in[17];
    const float* W_o   = (const float*)d_in[18];
    const float* b_o   = (const float*)d_in[19];
    float* out = (float*)d_out;

    char* ws = (char*)d_ws;
    size_t off = 0;
    auto alloc = [&](size_t bytes) { void* p = ws + off; off += (bytes + 255) & ~(size_t)255; return p; };
    short* wt_in  = (short*)alloc((size_t)4096 * 1024 * 2);
    short* wt_x   = (short*)alloc((size_t)1536 * 2048 * 2);
    short* wt_dt  = (short*)alloc((size_t)2048 * 512 * 2);
    short* wt_out = (short*)alloc((size_t)1024 * 2048 * 2);
    short* wt_d   = (short*)alloc((size_t)512 * 1024 * 2);
    short* wt_f   = (short*)alloc((size_t)1024 * 512 * 2);
    short* wt_o   = (short*)alloc((size_t)1024 * 512 * 2);
    float* xd_p   = (float*)alloc(2 * SL2 * 4);
    float* dacc_p = (float*)alloc(2 * SLD * 4);
    float* mo_p   = (float*)alloc(4 * SLM * 4);
    float* zd_p   = (float*)alloc(4 * SLZ * 4);
    float* gb     = (float*)alloc((size_t)128 * 1024 * 4);
    short* h_bf   = (short*)alloc(128 * 1024 * 2);
    short* c_bf   = (short*)alloc(128 * 512 * 2);
    float* u_f32  = (float*)alloc((size_t)128 * 2048 * 4);
    short* u_bf   = (short*)alloc(128 * 2048 * 2);
    float* sres   = (float*)alloc((size_t)128 * 2048 * 4);
    short* y_bf   = (short*)alloc(128 * 2048 * 2);
    short* z_bf   = (short*)alloc(128 * 512 * 2);

    // 1) LN + c->bf16 + T(W_in) + T(W_f)
    prep_kernel<<<1280, 256, 0, stream>>>(x, ln_g, ln_b, c, W_in, W_f,
                                          h_bf, c_bf, wt_in, wt_f);
    // 2) G1 full-K (+silu/conv epi) || G6 full-K || T(W_x) || T(W_dt)
    g1g6_kernel<<<1184, 256, 0, stream>>>(h_bf, wt_in, c_bf, wt_f,
                                          convw + 3 * 2048, convb, W_x, W_dt,
                                          u_f32, u_bf, sres, gb, wt_x, wt_dt);
    // 3) G2 split-2 || T(W_out) || T(W_d)
    g2_kernel<<<736, 256, 0, stream>>>(u_bf, wt_x, W_out, W_d, xd_p, wt_out, wt_d);
    // 4) G3 (sum-2 loader, BN=64)
    g3_kernel<<<64, 256, 0, stream>>>(xd_p, wt_dt, dacc_p);
    // 5) e3 (svec + y)
    e3_kernel<<<128, 256, 0, stream>>>(xd_p, dacc_p, b_dt, u_f32, sres, Dv, y_bf);
    // 6) G4 split-4
    g4_kernel<<<128, 256, 0, stream>>>(y_bf, wt_out, mo_p);
    // 7) G5 (sum-4 + residual loader, BN=64) || T(W_o)
    g5_kernel<<<160, 256, 0, stream>>>(mo_p, b_out, x, wt_d, W_o, zd_p, wt_o);
    // 8) e5 (FiLM gelu)
    e5_kernel<<<64, 256, 0, stream>>>(zd_p, b_d, gb, b_f, z_bf);
    // 9) G7 full-K (+b_o epi) -> out
    g7_kernel<<<32, 256, 0, stream>>>(z_bf, wt_o, b_o, out);
}